// Round 1
// baseline (328.697 us; speedup 1.0000x reference)
//
#include <hip/hip_runtime.h>
#include <math.h>

#define NROWS 16      // B*QL
#define NCOLS 6144    // q 4096 | k 1024 | v 1024
#define HID   4096
#define NKV   8
#define HD    128
#define PRIOR 4096
#define NCH   32      // KV chunks in attention kernel
#define CHUNK 128     // keys per chunk
#define SUB   64      // keys per subtile
#define KC1   128     // K-chunk for projection kernels
#define NKC   32      // 4096 / KC1

__device__ __forceinline__ float rdlane(float v, int l) {
    return __int_as_float(__builtin_amdgcn_readlane(__float_as_int(v), l));
}

// ---------------------------------------------------------------------------
// K1: fused QKV projection, split-K partials.  part[NKC][16][6144]
// grid (24, 32) x 128 threads; 2 cols/thread, float2 weight loads;
// activations via block-uniform loads (s_load path). unroll 4 -> 16 VMEM
// loads in flight per wave (latency hiding at 6 waves/CU occupancy).
// ---------------------------------------------------------------------------
__global__ __launch_bounds__(128)
void k_qkv_partial(const float* __restrict__ hid,
                   const float* __restrict__ wq,
                   const float* __restrict__ wk,
                   const float* __restrict__ wv,
                   float* __restrict__ part)
{
    const int t   = threadIdx.x;
    const int col = blockIdx.x * 256 + t * 2;   // 256-col tiles: weight choice block-uniform
    const int kc  = blockIdx.y;
    const int k0  = kc * KC1;
    const float* w; int wn, wcol;
    if (col < 4096)      { w = wq; wn = 4096; wcol = col; }
    else if (col < 5120) { w = wk; wn = 1024; wcol = col - 4096; }
    else                 { w = wv; wn = 1024; wcol = col - 5120; }
    const float* wp = w + wcol + (size_t)k0 * wn;

    float acc[NROWS][2];
#pragma unroll
    for (int m = 0; m < NROWS; m++) { acc[m][0] = 0.f; acc[m][1] = 0.f; }
#pragma unroll 4
    for (int kk = 0; kk < KC1; kk += 4) {
        const float2 w0 = *(const float2*)(wp + (size_t)(kk + 0) * wn);
        const float2 w1 = *(const float2*)(wp + (size_t)(kk + 1) * wn);
        const float2 w2 = *(const float2*)(wp + (size_t)(kk + 2) * wn);
        const float2 w3 = *(const float2*)(wp + (size_t)(kk + 3) * wn);
#pragma unroll
        for (int m = 0; m < NROWS; m++) {
            const float4 h4 = *(const float4*)(hid + (size_t)m * HID + k0 + kk);
            acc[m][0] = fmaf(h4.x, w0.x, fmaf(h4.y, w1.x, fmaf(h4.z, w2.x, fmaf(h4.w, w3.x, acc[m][0]))));
            acc[m][1] = fmaf(h4.x, w0.y, fmaf(h4.y, w1.y, fmaf(h4.z, w2.y, fmaf(h4.w, w3.y, acc[m][1]))));
        }
    }
    float* po = part + (size_t)kc * (NROWS * NCOLS) + col;
#pragma unroll
    for (int m = 0; m < NROWS; m++)
        *(float2*)(po + (size_t)m * NCOLS) = make_float2(acc[m][0], acc[m][1]);
}

// ---------------------------------------------------------------------------
// K2: reduce split-K partials + RoPE (q scaled by 1/sqrt(HD)).
// ---------------------------------------------------------------------------
__global__ __launch_bounds__(256)
void k_reduce_rope(const float* __restrict__ part, float* __restrict__ qkv)
{
    const int tid = blockIdx.x * 256 + threadIdx.x;
    const double L64 = 0.21586735246819178;   // ln(1e6)/64

    if (tid < 32768) {                         // ---- q pairs ----
        const int d = tid & 63, h = (tid >> 6) & 31, r = tid >> 11;
        const int c1 = h * HD + d;
        float s1 = 0.f, s2 = 0.f;
#pragma unroll 8
        for (int c = 0; c < NKC; c++) {
            const float* p = part + (size_t)c * (NROWS * NCOLS) + r * NCOLS + c1;
            s1 += p[0]; s2 += p[64];
        }
        const double ang = (double)(PRIOR + (r & 3)) * exp(-(double)d * L64);
        double sv, cv; sincos(ang, &sv, &cv);
        const float cf = (float)cv, sf = (float)sv, sc = 0.08838834764831845f;
        qkv[r * NCOLS + c1]      = (s1 * cf - s2 * sf) * sc;
        qkv[r * NCOLS + c1 + 64] = (s2 * cf + s1 * sf) * sc;
    } else if (tid < 40960) {                  // ---- k_active pairs ----
        const int idx = tid - 32768;
        const int d = idx & 63, kh = (idx >> 6) & 7, r = idx >> 9;
        const int c1 = 4096 + kh * HD + d;
        float s1 = 0.f, s2 = 0.f;
#pragma unroll 8
        for (int c = 0; c < NKC; c++) {
            const float* p = part + (size_t)c * (NROWS * NCOLS) + r * NCOLS + c1;
            s1 += p[0]; s2 += p[64];
        }
        const double ang = (double)(PRIOR + (r & 3)) * exp(-(double)d * L64);
        double sv, cv; sincos(ang, &sv, &cv);
        const float cf = (float)cv, sf = (float)sv;
        qkv[r * NCOLS + c1]      = s1 * cf - s2 * sf;
        qkv[r * NCOLS + c1 + 64] = s2 * cf + s1 * sf;
    } else {                                   // ---- v_active ----
        const int idx = tid - 40960;
        const int n = idx & 1023, r = idx >> 10;
        const int c1 = 5120 + n;
        float s = 0.f;
#pragma unroll 8
        for (int c = 0; c < NKC; c++)
            s += part[(size_t)c * (NROWS * NCOLS) + r * NCOLS + c1];
        qkv[r * NCOLS + c1] = s;
    }
}

// ---------------------------------------------------------------------------
// K3: flash-decoding over prior KV.  grid (32, 8, 4) = 1024 blocks = 4/CU.
// LDS exactly 40 KB (kT 32K + qT 8K, no aliases).
// v2 restructure:
//  - K subtile register-prefetch: loads for st+1 issued before bar-a of st,
//    land during score+PV (async-stage / T14 pattern).
//  - PV is per-wave (wave owns its 4 rows): after the d-quarter shfl reduce
//    every wave holds the full 64-key prob row in registers; probs broadcast
//    with v_readlane (compile-time src lane), V read directly from global
//    (identical coalesced addresses across waves -> L1 broadcast).
//  - Eliminates pP/aS LDS prob buffer, bar-c, bar-d, and the end-of-block
//    cross-partition reduce (3 barriers + stride-36 conflicts).
//  => 2 barriers/subtile (4/block) vs 11/block before.
// ---------------------------------------------------------------------------
__global__ __launch_bounds__(256, 4)
void k_attn_prior(const float* __restrict__ qkv,
                  const float* __restrict__ pk,
                  const float* __restrict__ pv,
                  float* __restrict__ part3)
{
    const int chunk = blockIdx.x, kvh = blockIdx.y, b = blockIdx.z;
    const int t = threadIdx.x;
    const int lane = t & 63;

    __shared__ float kT[128][64];   // [d][key] 32 KB (stride 64: 2-way = free)
    __shared__ float qT[128][16];   // [d][row]  8 KB (broadcast reads)

    const int qt = t >> 6;          // wave id = row group (rows qt*4..+3)
    const int h  = (lane >> 4) & 3; // d-quarter (lane subfield)
    const int kt = lane & 15;       // key group (keys kt*4..+3)

    const size_t kvoff = ((size_t)(b * NKV + kvh) * PRIOR + (size_t)chunk * CHUNK) * HD;
    const float* kbase = pk + kvoff;
    const float* vbase = pv + kvoff;

    // prefetch K subtile 0 into registers (overlaps qT staging)
    float4 kreg[8];
    {
        const float* kr = kbase + (size_t)lane * HD + qt * 32;
#pragma unroll
        for (int i = 0; i < 8; i++) kreg[i] = *(const float4*)(kr + i * 4);
    }

    // stage Q transposed (once)
    for (int i = t; i < 2048; i += 256) {
        const int r = i & 15, d = i >> 4;
        const int ql = r & 3, g = r >> 2;
        qT[d][r] = qkv[(size_t)(b * 4 + ql) * NCOLS + (kvh * 4 + g) * HD + d];
    }

    float m_r[4], l_r[4], o[4][2];
#pragma unroll
    for (int i = 0; i < 4; i++) { m_r[i] = -INFINITY; l_r[i] = 0.f; o[i][0] = 0.f; o[i][1] = 0.f; }

    for (int st = 0; st < CHUNK / SUB; st++) {
        // ---- write prefetched K^T into LDS; issue next subtile's loads ----
#pragma unroll
        for (int i = 0; i < 8; i++) {
            const int d = qt * 32 + i * 4;
            kT[d + 0][lane] = kreg[i].x; kT[d + 1][lane] = kreg[i].y;
            kT[d + 2][lane] = kreg[i].z; kT[d + 3][lane] = kreg[i].w;
        }
        if (st == 0) {   // in flight across score + PV of subtile 0
            const float* kr = kbase + (size_t)(SUB + lane) * HD + qt * 32;
#pragma unroll
            for (int i = 0; i < 8; i++) kreg[i] = *(const float4*)(kr + i * 4);
        }
        __syncthreads();   // bar-a: kT (and qT on st=0) ready

        // ---- scores: 4 rows x 4 keys per thread, d-quarter h ----
        float a[4][4];
#pragma unroll
        for (int i = 0; i < 4; i++)
#pragma unroll
            for (int j = 0; j < 4; j++) a[i][j] = 0.f;
#pragma unroll 4
        for (int dd = 0; dd < 32; dd++) {
            const int d = h * 32 + dd;
            const float4 q4 = *(const float4*)(&qT[d][qt * 4]);
            const float4 k4 = *(const float4*)(&kT[d][kt * 4]);
            a[0][0]=fmaf(q4.x,k4.x,a[0][0]); a[0][1]=fmaf(q4.x,k4.y,a[0][1]); a[0][2]=fmaf(q4.x,k4.z,a[0][2]); a[0][3]=fmaf(q4.x,k4.w,a[0][3]);
            a[1][0]=fmaf(q4.y,k4.x,a[1][0]); a[1][1]=fmaf(q4.y,k4.y,a[1][1]); a[1][2]=fmaf(q4.y,k4.z,a[1][2]); a[1][3]=fmaf(q4.y,k4.w,a[1][3]);
            a[2][0]=fmaf(q4.z,k4.x,a[2][0]); a[2][1]=fmaf(q4.z,k4.y,a[2][1]); a[2][2]=fmaf(q4.z,k4.z,a[2][2]); a[2][3]=fmaf(q4.z,k4.w,a[2][3]);
            a[3][0]=fmaf(q4.w,k4.x,a[3][0]); a[3][1]=fmaf(q4.w,k4.y,a[3][1]); a[3][2]=fmaf(q4.w,k4.z,a[3][2]); a[3][3]=fmaf(q4.w,k4.w,a[3][3]);
        }
        __syncthreads();   // bar-b: kT reads done -> next iteration may restage

        // ---- reduce d-quarters via xor shuffles (lanes ^16, ^32) ----
#pragma unroll
        for (int i = 0; i < 4; i++)
#pragma unroll
            for (int j = 0; j < 4; j++) {
                float v = a[i][j];
                v += __shfl_xor(v, 16);
                v += __shfl_xor(v, 32);
                a[i][j] = v;
            }
        // ---- wave-private online softmax (per-row, replicated across lanes) ----
        float al[4], pr[4][4];
#pragma unroll
        for (int i = 0; i < 4; i++) {
            float mx = fmaxf(fmaxf(a[i][0], a[i][1]), fmaxf(a[i][2], a[i][3]));
            mx = fmaxf(mx, __shfl_xor(mx, 1));
            mx = fmaxf(mx, __shfl_xor(mx, 2));
            mx = fmaxf(mx, __shfl_xor(mx, 4));
            mx = fmaxf(mx, __shfl_xor(mx, 8));
            const float mn = fmaxf(m_r[i], mx);
            al[i] = __expf(m_r[i] - mn);      // first subtile: exp(-inf)=0
            m_r[i] = mn;
            float s = 0.f;
#pragma unroll
            for (int j = 0; j < 4; j++) { pr[i][j] = __expf(a[i][j] - mn); s += pr[i][j]; }
            s += __shfl_xor(s, 1); s += __shfl_xor(s, 2);
            s += __shfl_xor(s, 4); s += __shfl_xor(s, 8);
            l_r[i] = l_r[i] * al[i] + s;
        }
        // ---- rescale running output ----
#pragma unroll
        for (int i = 0; i < 4; i++) { o[i][0] *= al[i]; o[i][1] *= al[i]; }

        // ---- PV in-wave: lane owns d pair (2*lane); probs via readlane ----
        // V addresses identical across the 4 waves (L1 broadcast), 512 B
        // contiguous per key per wave-inst.
        const float* vs = vbase + (size_t)st * SUB * HD + (lane << 1);
#pragma unroll
        for (int g4 = 0; g4 < 16; g4++) {
            const float2 v0 = *(const float2*)(vs + (size_t)(g4 * 4 + 0) * HD);
            const float2 v1 = *(const float2*)(vs + (size_t)(g4 * 4 + 1) * HD);
            const float2 v2 = *(const float2*)(vs + (size_t)(g4 * 4 + 2) * HD);
            const float2 v3 = *(const float2*)(vs + (size_t)(g4 * 4 + 3) * HD);
#pragma unroll
            for (int i = 0; i < 4; i++) {
                const float p0 = rdlane(pr[i][0], g4);
                const float p1 = rdlane(pr[i][1], g4);
                const float p2 = rdlane(pr[i][2], g4);
                const float p3v = rdlane(pr[i][3], g4);
                o[i][0] = fmaf(p0,  v0.x, o[i][0]); o[i][1] = fmaf(p0,  v0.y, o[i][1]);
                o[i][0] = fmaf(p1,  v1.x, o[i][0]); o[i][1] = fmaf(p1,  v1.y, o[i][1]);
                o[i][0] = fmaf(p2,  v2.x, o[i][0]); o[i][1] = fmaf(p2,  v2.y, o[i][1]);
                o[i][0] = fmaf(p3v, v3.x, o[i][0]); o[i][1] = fmaf(p3v, v3.y, o[i][1]);
            }
        }
    }

    // ---- direct writeout from registers (no cross-wave reduce needed) ----
    float* pout = part3 + (size_t)((b * NKV + kvh) * NCH + chunk) * 2080;
    if (lane == 0) {
#pragma unroll
        for (int i = 0; i < 4; i++) { pout[qt * 4 + i] = m_r[i]; pout[16 + qt * 4 + i] = l_r[i]; }
    }
#pragma unroll
    for (int i = 0; i < 4; i++)
        *(float2*)(pout + 32 + (size_t)(qt * 4 + i) * HD + (lane << 1)) =
            make_float2(o[i][0], o[i][1]);
}

// ---------------------------------------------------------------------------
// K4: combine chunk partials + causal active keys (shared max / divisor).
// grid 128 blocks = (g, kvh, b); each handles 4 rows (fixed head g).
// v2: serial phases parallelized -- active scores on 128 lanes (8 lanes per
// (row,key) pair + shfl reduce), per-row stats on 32 lanes/row + shfl reduce.
// ---------------------------------------------------------------------------
__global__ __launch_bounds__(256)
void k_combine(const float* __restrict__ qkv,
               const float* __restrict__ part3,
               float* __restrict__ attn)
{
    const int g = blockIdx.x & 3, kvh = (blockIdx.x >> 2) & 7, b = blockIdx.x >> 5;
    const int t = threadIdx.x;
    __shared__ float qL[4][128], kA[4][128], vA[4][128];
    __shared__ float mC[NCH][4], lC[NCH][4], fC[NCH][4];
    __shared__ float sAct[4][4], pA[4][4], invL[4];

    for (int i = t; i < 512; i += 256) {
        const int ql = i >> 7, d = i & 127;
        qL[ql][d] = qkv[(size_t)(b * 4 + ql) * NCOLS + (kvh * 4 + g) * HD + d];
        kA[ql][d] = qkv[(size_t)(b * 4 + ql) * NCOLS + 4096 + kvh * HD + d];
        vA[ql][d] = qkv[(size_t)(b * 4 + ql) * NCOLS + 5120 + kvh * HD + d];
    }
    const float* p3 = part3 + (size_t)(b * NKV + kvh) * NCH * 2080;
    for (int i = t; i < NCH * 4; i += 256) {
        const int c = i >> 2, lr = i & 3;
        mC[c][lr] = p3[c * 2080 + g * 4 + lr];
        lC[c][lr] = p3[c * 2080 + 16 + g * 4 + lr];
    }
    __syncthreads();
    if (t < 128) {                       // active scores: 8 lanes per (lr,k)
        const int pp = t >> 3, dd = t & 7;
        const int lr = pp >> 2, k = pp & 3;
        float s = 0.f;
#pragma unroll
        for (int d = 0; d < 16; d++)
            s = fmaf(qL[lr][dd * 16 + d], kA[k][dd * 16 + d], s);
        s += __shfl_xor(s, 1); s += __shfl_xor(s, 2); s += __shfl_xor(s, 4);
        if (dd == 0) sAct[lr][k] = s;
    }
    __syncthreads();
    if (t < 128) {                       // per-row stats: 32 lanes per row
        const int lr = t >> 5, c = t & 31;
        const float m  = mC[c][lr];
        const bool act = (c < 4) && (c <= lr);
        const float sa = act ? sAct[lr][c] : -INFINITY;
        float M = fmaxf(m, sa);
        M = fmaxf(M, __shfl_xor(M, 1));
        M = fmaxf(M, __shfl_xor(M, 2));
        M = fmaxf(M, __shfl_xor(M, 4));
        M = fmaxf(M, __shfl_xor(M, 8));
        M = fmaxf(M, __shfl_xor(M, 16));
        const float f = __expf(m - M);
        fC[c][lr] = f;
        const float pact = act ? __expf(sa - M) : 0.f;
        if (c < 4) pA[lr][c] = pact;
        float l = fmaf(f, lC[c][lr], pact);
        l += __shfl_xor(l, 1); l += __shfl_xor(l, 2);
        l += __shfl_xor(l, 4); l += __shfl_xor(l, 8); l += __shfl_xor(l, 16);
        if (c == 0) invL[lr] = 1.f / l;
    }
    __syncthreads();

    const int d = t & 127, hr = t >> 7;
    const int lr0 = hr * 2, lr1 = hr * 2 + 1;
    float o0 = 0.f, o1 = 0.f;
#pragma unroll 4
    for (int c = 0; c < NCH; c++) {
        const float f0 = fC[c][lr0], f1 = fC[c][lr1];
        const float* pa = p3 + c * 2080 + 32 + (g * 4 + lr0) * HD + d;
        o0 = fmaf(f0, pa[0],  o0);
        o1 = fmaf(f1, pa[HD], o1);
    }
#pragma unroll
    for (int k = 0; k < 4; k++) {
        const float v = vA[k][d];
        o0 = fmaf(pA[lr0][k], v, o0);
        o1 = fmaf(pA[lr1][k], v, o1);
    }
    attn[(size_t)(b * 4 + lr0) * HID + (kvh * 4 + g) * HD + d] = o0 * invL[lr0];
    attn[(size_t)(b * 4 + lr1) * HID + (kvh * 4 + g) * HD + d] = o1 * invL[lr1];
}

// ---------------------------------------------------------------------------
// K5: output projection split-K partials.  part[NKC][16][4096], grid (16,32)x128.
// ---------------------------------------------------------------------------
__global__ __launch_bounds__(128)
void k_out_partial(const float* __restrict__ attn,
                   const float* __restrict__ wo,
                   float* __restrict__ part)
{
    const int t = threadIdx.x;
    const int col = blockIdx.x * 256 + t * 2;
    const int kc = blockIdx.y;
    const int k0 = kc * KC1;
    const float* wp = wo + col + (size_t)k0 * HID;

    float acc[NROWS][2];
#pragma unroll
    for (int m = 0; m < NROWS; m++) { acc[m][0] = 0.f; acc[m][1] = 0.f; }
#pragma unroll 4
    for (int kk = 0; kk < KC1; kk += 4) {
        const float2 w0 = *(const float2*)(wp + (size_t)(kk + 0) * HID);
        const float2 w1 = *(const float2*)(wp + (size_t)(kk + 1) * HID);
        const float2 w2 = *(const float2*)(wp + (size_t)(kk + 2) * HID);
        const float2 w3 = *(const float2*)(wp + (size_t)(kk + 3) * HID);
#pragma unroll
        for (int m = 0; m < NROWS; m++) {
            const float4 h4 = *(const float4*)(attn + (size_t)m * HID + k0 + kk);
            acc[m][0] = fmaf(h4.x, w0.x, fmaf(h4.y, w1.x, fmaf(h4.z, w2.x, fmaf(h4.w, w3.x, acc[m][0]))));
            acc[m][1] = fmaf(h4.x, w0.y, fmaf(h4.y, w1.y, fmaf(h4.z, w2.y, fmaf(h4.w, w3.y, acc[m][1]))));
        }
    }
    float* po = part + (size_t)kc * (NROWS * HID) + col;
#pragma unroll
    for (int m = 0; m < NROWS; m++)
        *(float2*)(po + (size_t)m * HID) = make_float2(acc[m][0], acc[m][1]);
}

// K5b: reduce out-proj partials -> d_out (float4)
__global__ __launch_bounds__(256)
void k_out_reduce(const float* __restrict__ part, float* __restrict__ out)
{
    const int tid = blockIdx.x * 256 + threadIdx.x;   // 16384
    const float* p = part + (size_t)tid * 4;
    float4 s = make_float4(0.f, 0.f, 0.f, 0.f);
#pragma unroll 8
    for (int c = 0; c < NKC; c++) {
        const float4 a = *(const float4*)(p + (size_t)c * (NROWS * HID));
        s.x += a.x; s.y += a.y; s.z += a.z; s.w += a.w;
    }
    *(float4*)(out + (size_t)tid * 4) = s;
}

// ---------------------------------------------------------------------------
extern "C" void kernel_launch(void* const* d_in, const int* in_sizes, int n_in,
                              void* d_out, int out_size, void* d_ws, size_t ws_size,
                              hipStream_t stream)
{
    (void)in_sizes; (void)n_in; (void)out_size; (void)ws_size;
    const float* hid = (const float*)d_in[0];
    const float* pk  = (const float*)d_in[1];
    const float* pv  = (const float*)d_in[2];
    const float* wq  = (const float*)d_in[3];
    const float* wk  = (const float*)d_in[4];
    const float* wv  = (const float*)d_in[5];
    const float* wo  = (const float*)d_in[6];
    float* out = (float*)d_out;
    float* ws  = (float*)d_ws;

    // workspace (floats); sequential lifetimes share region 0:
    //   P1 [k1->k2] 3,145,728 | P3 [k3->k4] 2,129,920 | P5 [k5->k5b] 2,097,152
    float* P1   = ws;
    float* P3   = ws;
    float* P5   = ws;
    float* qkv  = ws + 3145728;            // 98,304
    float* attn = ws + 3244032;            // 65,536   (total 13.24 MB)

    k_qkv_partial<<<dim3(24, NKC), 128, 0, stream>>>(hid, wq, wk, wv, P1);
    k_reduce_rope<<<224, 256, 0, stream>>>(P1, qkv);
    k_attn_prior<<<dim3(NCH, NKV, 4), 256, 0, stream>>>(qkv, pk, pv, P3);
    k_combine<<<128, 256, 0, stream>>>(qkv, P3, attn);
    k_out_partial<<<dim3(16, NKC), 128, 0, stream>>>(attn, wo, P5);
    k_out_reduce<<<64, 256, 0, stream>>>(P5, out);
}

// Round 2
// 314.880 us; speedup vs baseline: 1.0439x; 1.0439x over previous
//
#include <hip/hip_runtime.h>
#include <math.h>

#define NROWS 16      // B*QL
#define NCOLS 6144    // q 4096 | k 1024 | v 1024
#define HID   4096
#define NKV   8
#define HD    128
#define PRIOR 4096
#define NCH   32      // KV chunks in attention kernel
#define CHUNK 128     // keys per chunk
#define SUB   64      // keys per subtile
#define KCQ   64      // K-chunk for qkv projection
#define NKCQ  64      // 4096 / KCQ  -> 1536 blocks (3 waves/SIMD)
#define KCO   64      // K-chunk for out projection
#define NKCO  64      // 4096 / KCO  -> 1024 blocks (2 waves/SIMD)

__device__ __forceinline__ float rdlane(float v, int l) {
    return __int_as_float(__builtin_amdgcn_readlane(__float_as_int(v), l));
}

// ---------------------------------------------------------------------------
// K1: fused QKV projection, split-K partials.  part[NKCQ][16][6144]
// grid (24, 64) x 128 threads = 1536 blocks = 6 blocks/CU = 3 waves/SIMD.
// 2 cols/thread, float2 weight loads; activations block-uniform (s_load).
// ---------------------------------------------------------------------------
__global__ __launch_bounds__(128)
void k_qkv_partial(const float* __restrict__ hid,
                   const float* __restrict__ wq,
                   const float* __restrict__ wk,
                   const float* __restrict__ wv,
                   float* __restrict__ part)
{
    const int t   = threadIdx.x;
    const int col = blockIdx.x * 256 + t * 2;   // 256-col tiles: weight choice block-uniform
    const int kc  = blockIdx.y;
    const int k0  = kc * KCQ;
    const float* w; int wn, wcol;
    if (col < 4096)      { w = wq; wn = 4096; wcol = col; }
    else if (col < 5120) { w = wk; wn = 1024; wcol = col - 4096; }
    else                 { w = wv; wn = 1024; wcol = col - 5120; }
    const float* wp = w + wcol + (size_t)k0 * wn;

    float acc[NROWS][2];
#pragma unroll
    for (int m = 0; m < NROWS; m++) { acc[m][0] = 0.f; acc[m][1] = 0.f; }
#pragma unroll 4
    for (int kk = 0; kk < KCQ; kk += 4) {
        const float2 w0 = *(const float2*)(wp + (size_t)(kk + 0) * wn);
        const float2 w1 = *(const float2*)(wp + (size_t)(kk + 1) * wn);
        const float2 w2 = *(const float2*)(wp + (size_t)(kk + 2) * wn);
        const float2 w3 = *(const float2*)(wp + (size_t)(kk + 3) * wn);
#pragma unroll
        for (int m = 0; m < NROWS; m++) {
            const float4 h4 = *(const float4*)(hid + (size_t)m * HID + k0 + kk);
            acc[m][0] = fmaf(h4.x, w0.x, fmaf(h4.y, w1.x, fmaf(h4.z, w2.x, fmaf(h4.w, w3.x, acc[m][0]))));
            acc[m][1] = fmaf(h4.x, w0.y, fmaf(h4.y, w1.y, fmaf(h4.z, w2.y, fmaf(h4.w, w3.y, acc[m][1]))));
        }
    }
    float* po = part + (size_t)kc * (NROWS * NCOLS) + col;
#pragma unroll
    for (int m = 0; m < NROWS; m++)
        *(float2*)(po + (size_t)m * NCOLS) = make_float2(acc[m][0], acc[m][1]);
}

// ---------------------------------------------------------------------------
// K2: reduce split-K partials + RoPE (q scaled by 1/sqrt(HD)).
// v3: 4 lanes per output (lane&15 = output within wave-slot, lane>>4 = chunk
// quarter), shfl_xor(16/32) combine.  57344 outputs x 4 = 896 blocks x 256
// = 3.5 waves/SIMD; 16-iteration loops instead of 32/64.
// ---------------------------------------------------------------------------
__global__ __launch_bounds__(256)
void k_reduce_rope(const float* __restrict__ part, float* __restrict__ qkv)
{
    const int tid  = blockIdx.x * 256 + threadIdx.x;
    const int w    = tid >> 6, lane = tid & 63;
    const int u    = w * 16 + (lane & 15);     // output unit, 0..57343
    const int sub  = lane >> 4;                // chunk quarter
    const int cs   = sub * 16;
    const double L64 = 0.21586735246819178;    // ln(1e6)/64

    if (u < 32768) {                           // ---- q pairs ----
        const int d = u & 63, h = (u >> 6) & 31, r = u >> 11;
        const int c1 = h * HD + d;
        float s1 = 0.f, s2 = 0.f;
#pragma unroll 8
        for (int i = 0; i < 16; i++) {
            const float* p = part + (size_t)(cs + i) * (NROWS * NCOLS) + r * NCOLS + c1;
            s1 += p[0]; s2 += p[64];
        }
        s1 += __shfl_xor(s1, 16); s1 += __shfl_xor(s1, 32);
        s2 += __shfl_xor(s2, 16); s2 += __shfl_xor(s2, 32);
        if (sub == 0) {
            const double ang = (double)(PRIOR + (r & 3)) * exp(-(double)d * L64);
            double sv, cv; sincos(ang, &sv, &cv);
            const float cf = (float)cv, sf = (float)sv, sc = 0.08838834764831845f;
            qkv[r * NCOLS + c1]      = (s1 * cf - s2 * sf) * sc;
            qkv[r * NCOLS + c1 + 64] = (s2 * cf + s1 * sf) * sc;
        }
    } else if (u < 40960) {                    // ---- k_active pairs ----
        const int idx = u - 32768;
        const int d = idx & 63, kh = (idx >> 6) & 7, r = idx >> 9;
        const int c1 = 4096 + kh * HD + d;
        float s1 = 0.f, s2 = 0.f;
#pragma unroll 8
        for (int i = 0; i < 16; i++) {
            const float* p = part + (size_t)(cs + i) * (NROWS * NCOLS) + r * NCOLS + c1;
            s1 += p[0]; s2 += p[64];
        }
        s1 += __shfl_xor(s1, 16); s1 += __shfl_xor(s1, 32);
        s2 += __shfl_xor(s2, 16); s2 += __shfl_xor(s2, 32);
        if (sub == 0) {
            const double ang = (double)(PRIOR + (r & 3)) * exp(-(double)d * L64);
            double sv, cv; sincos(ang, &sv, &cv);
            const float cf = (float)cv, sf = (float)sv;
            qkv[r * NCOLS + c1]      = s1 * cf - s2 * sf;
            qkv[r * NCOLS + c1 + 64] = s2 * cf + s1 * sf;
        }
    } else {                                   // ---- v_active ----
        const int idx = u - 40960;
        const int n = idx & 1023, r = idx >> 10;
        const int c1 = 5120 + n;
        float s = 0.f;
#pragma unroll 8
        for (int i = 0; i < 16; i++)
            s += part[(size_t)(cs + i) * (NROWS * NCOLS) + r * NCOLS + c1];
        s += __shfl_xor(s, 16); s += __shfl_xor(s, 32);
        if (sub == 0) qkv[r * NCOLS + c1] = s;
    }
}

// ---------------------------------------------------------------------------
// K3: flash-decoding over prior KV.  grid (32, 8, 4) = 1024 blocks = 4/CU.
// v3: PV V-loads software-pipelined -- first 4 key-groups issued right after
// bar-b (overlap the softmax shuffle/exp chain), consume loop fully unrolled
// with 4-group lookahead reload (static vb indices -> registers).
// ---------------------------------------------------------------------------
__global__ __launch_bounds__(256, 4)
void k_attn_prior(const float* __restrict__ qkv,
                  const float* __restrict__ pk,
                  const float* __restrict__ pv,
                  float* __restrict__ part3)
{
    const int chunk = blockIdx.x, kvh = blockIdx.y, b = blockIdx.z;
    const int t = threadIdx.x;
    const int lane = t & 63;

    __shared__ float kT[128][64];   // [d][key] 32 KB (stride 64: 2-way = free)
    __shared__ float qT[128][16];   // [d][row]  8 KB (broadcast reads)

    const int qt = t >> 6;          // wave id = row group (rows qt*4..+3)
    const int h  = (lane >> 4) & 3; // d-quarter (lane subfield)
    const int kt = lane & 15;       // key group (keys kt*4..+3)

    const size_t kvoff = ((size_t)(b * NKV + kvh) * PRIOR + (size_t)chunk * CHUNK) * HD;
    const float* kbase = pk + kvoff;
    const float* vbase = pv + kvoff;

    // prefetch K subtile 0 into registers (overlaps qT staging)
    float4 kreg[8];
    {
        const float* kr = kbase + (size_t)lane * HD + qt * 32;
#pragma unroll
        for (int i = 0; i < 8; i++) kreg[i] = *(const float4*)(kr + i * 4);
    }

    // stage Q transposed (once)
    for (int i = t; i < 2048; i += 256) {
        const int r = i & 15, d = i >> 4;
        const int ql = r & 3, g = r >> 2;
        qT[d][r] = qkv[(size_t)(b * 4 + ql) * NCOLS + (kvh * 4 + g) * HD + d];
    }

    float m_r[4], l_r[4], o[4][2];
#pragma unroll
    for (int i = 0; i < 4; i++) { m_r[i] = -INFINITY; l_r[i] = 0.f; o[i][0] = 0.f; o[i][1] = 0.f; }

    for (int st = 0; st < CHUNK / SUB; st++) {
        // ---- write prefetched K^T into LDS; issue next subtile's loads ----
#pragma unroll
        for (int i = 0; i < 8; i++) {
            const int d = qt * 32 + i * 4;
            kT[d + 0][lane] = kreg[i].x; kT[d + 1][lane] = kreg[i].y;
            kT[d + 2][lane] = kreg[i].z; kT[d + 3][lane] = kreg[i].w;
        }
        if (st == 0) {   // in flight across score + PV of subtile 0
            const float* kr = kbase + (size_t)(SUB + lane) * HD + qt * 32;
#pragma unroll
            for (int i = 0; i < 8; i++) kreg[i] = *(const float4*)(kr + i * 4);
        }
        __syncthreads();   // bar-a: kT (and qT on st=0) ready

        // ---- scores: 4 rows x 4 keys per thread, d-quarter h ----
        float a[4][4];
#pragma unroll
        for (int i = 0; i < 4; i++)
#pragma unroll
            for (int j = 0; j < 4; j++) a[i][j] = 0.f;
#pragma unroll 4
        for (int dd = 0; dd < 32; dd++) {
            const int d = h * 32 + dd;
            const float4 q4 = *(const float4*)(&qT[d][qt * 4]);
            const float4 k4 = *(const float4*)(&kT[d][kt * 4]);
            a[0][0]=fmaf(q4.x,k4.x,a[0][0]); a[0][1]=fmaf(q4.x,k4.y,a[0][1]); a[0][2]=fmaf(q4.x,k4.z,a[0][2]); a[0][3]=fmaf(q4.x,k4.w,a[0][3]);
            a[1][0]=fmaf(q4.y,k4.x,a[1][0]); a[1][1]=fmaf(q4.y,k4.y,a[1][1]); a[1][2]=fmaf(q4.y,k4.z,a[1][2]); a[1][3]=fmaf(q4.y,k4.w,a[1][3]);
            a[2][0]=fmaf(q4.z,k4.x,a[2][0]); a[2][1]=fmaf(q4.z,k4.y,a[2][1]); a[2][2]=fmaf(q4.z,k4.z,a[2][2]); a[2][3]=fmaf(q4.z,k4.w,a[2][3]);
            a[3][0]=fmaf(q4.w,k4.x,a[3][0]); a[3][1]=fmaf(q4.w,k4.y,a[3][1]); a[3][2]=fmaf(q4.w,k4.z,a[3][2]); a[3][3]=fmaf(q4.w,k4.w,a[3][3]);
        }
        __syncthreads();   // bar-b: kT reads done -> next iteration may restage

        // ---- issue first 4 V key-groups (latency hides under softmax) ----
        const float* vs = vbase + (size_t)st * SUB * HD + (lane << 1);
        float2 vb[4][4];
#pragma unroll
        for (int g = 0; g < 4; ++g)
#pragma unroll
            for (int j = 0; j < 4; ++j)
                vb[g][j] = *(const float2*)(vs + (size_t)(g * 4 + j) * HD);

        // ---- reduce d-quarters via xor shuffles (lanes ^16, ^32) ----
#pragma unroll
        for (int i = 0; i < 4; i++)
#pragma unroll
            for (int j = 0; j < 4; j++) {
                float v = a[i][j];
                v += __shfl_xor(v, 16);
                v += __shfl_xor(v, 32);
                a[i][j] = v;
            }
        // ---- wave-private online softmax (per-row, replicated across lanes) ----
        float al[4], pr[4][4];
#pragma unroll
        for (int i = 0; i < 4; i++) {
            float mx = fmaxf(fmaxf(a[i][0], a[i][1]), fmaxf(a[i][2], a[i][3]));
            mx = fmaxf(mx, __shfl_xor(mx, 1));
            mx = fmaxf(mx, __shfl_xor(mx, 2));
            mx = fmaxf(mx, __shfl_xor(mx, 4));
            mx = fmaxf(mx, __shfl_xor(mx, 8));
            const float mn = fmaxf(m_r[i], mx);
            al[i] = __expf(m_r[i] - mn);      // first subtile: exp(-inf)=0
            m_r[i] = mn;
            float s = 0.f;
#pragma unroll
            for (int j = 0; j < 4; j++) { pr[i][j] = __expf(a[i][j] - mn); s += pr[i][j]; }
            s += __shfl_xor(s, 1); s += __shfl_xor(s, 2);
            s += __shfl_xor(s, 4); s += __shfl_xor(s, 8);
            l_r[i] = l_r[i] * al[i] + s;
        }
        // ---- rescale running output ----
#pragma unroll
        for (int i = 0; i < 4; i++) { o[i][0] *= al[i]; o[i][1] *= al[i]; }

        // ---- PV consume with 4-group lookahead (all indices static) ----
#pragma unroll
        for (int g4 = 0; g4 < 16; ++g4) {
            const float2 v0 = vb[g4 & 3][0];
            const float2 v1 = vb[g4 & 3][1];
            const float2 v2 = vb[g4 & 3][2];
            const float2 v3 = vb[g4 & 3][3];
            if (g4 < 12) {
#pragma unroll
                for (int j = 0; j < 4; ++j)
                    vb[g4 & 3][j] = *(const float2*)(vs + (size_t)((g4 + 4) * 4 + j) * HD);
            }
#pragma unroll
            for (int i = 0; i < 4; i++) {
                const float p0 = rdlane(pr[i][0], g4);
                const float p1 = rdlane(pr[i][1], g4);
                const float p2 = rdlane(pr[i][2], g4);
                const float p3v = rdlane(pr[i][3], g4);
                o[i][0] = fmaf(p0,  v0.x, o[i][0]); o[i][1] = fmaf(p0,  v0.y, o[i][1]);
                o[i][0] = fmaf(p1,  v1.x, o[i][0]); o[i][1] = fmaf(p1,  v1.y, o[i][1]);
                o[i][0] = fmaf(p2,  v2.x, o[i][0]); o[i][1] = fmaf(p2,  v2.y, o[i][1]);
                o[i][0] = fmaf(p3v, v3.x, o[i][0]); o[i][1] = fmaf(p3v, v3.y, o[i][1]);
            }
        }
    }

    // ---- direct writeout from registers (no cross-wave reduce needed) ----
    float* pout = part3 + (size_t)((b * NKV + kvh) * NCH + chunk) * 2080;
    if (lane == 0) {
#pragma unroll
        for (int i = 0; i < 4; i++) { pout[qt * 4 + i] = m_r[i]; pout[16 + qt * 4 + i] = l_r[i]; }
    }
#pragma unroll
    for (int i = 0; i < 4; i++)
        *(float2*)(pout + 32 + (size_t)(qt * 4 + i) * HD + (lane << 1)) =
            make_float2(o[i][0], o[i][1]);
}

// ---------------------------------------------------------------------------
// K4: combine chunk partials + causal active keys (shared max / divisor).
// v3: 256 blocks x 128 threads = 1 block/CU; block = (hr, g, kvh, b) handles
// one row-pair.  Scores/stats on wave 0 with shfl reduces.
// ---------------------------------------------------------------------------
__global__ __launch_bounds__(128)
void k_combine(const float* __restrict__ qkv,
               const float* __restrict__ part3,
               float* __restrict__ attn)
{
    const int bid = blockIdx.x;
    const int hr = bid & 1, g = (bid >> 1) & 3, kvh = (bid >> 3) & 7, b = bid >> 6;
    const int t = threadIdx.x;
    const int lr0 = hr * 2, lr1 = lr0 + 1;
    __shared__ float qL[2][128], kA[4][128], vA[4][128];
    __shared__ float mC[NCH][2], lC[NCH][2], fC[NCH][2];
    __shared__ float sAct[2][4], pA[2][4], invL[2];

    for (int i = t; i < 256; i += 128) {
        const int lrl = i >> 7, d = i & 127;
        qL[lrl][d] = qkv[(size_t)(b * 4 + lr0 + lrl) * NCOLS + (kvh * 4 + g) * HD + d];
    }
    for (int i = t; i < 512; i += 128) {
        const int ql = i >> 7, d = i & 127;
        kA[ql][d] = qkv[(size_t)(b * 4 + ql) * NCOLS + 4096 + kvh * HD + d];
        vA[ql][d] = qkv[(size_t)(b * 4 + ql) * NCOLS + 5120 + kvh * HD + d];
    }
    const float* p3 = part3 + (size_t)(b * NKV + kvh) * NCH * 2080;
    for (int i = t; i < NCH * 2; i += 128) {
        const int c = i >> 1, lrl = i & 1;
        mC[c][lrl] = p3[c * 2080 + g * 4 + lr0 + lrl];
        lC[c][lrl] = p3[c * 2080 + 16 + g * 4 + lr0 + lrl];
    }
    __syncthreads();
    if (t < 64) {                        // active scores: 8 lanes per (lrl,k)
        const int pp = t >> 3, dd = t & 7;
        const int lrl = pp >> 2, k = pp & 3;
        float s = 0.f;
#pragma unroll
        for (int d = 0; d < 16; d++)
            s = fmaf(qL[lrl][dd * 16 + d], kA[k][dd * 16 + d], s);
        s += __shfl_xor(s, 1); s += __shfl_xor(s, 2); s += __shfl_xor(s, 4);
        if (dd == 0) sAct[lrl][k] = s;
    }
    __syncthreads();
    if (t < 64) {                        // per-row stats: 32 lanes per row
        const int lrl = t >> 5, c = t & 31;
        const int lr = lr0 + lrl;
        const float m  = mC[c][lrl];
        const bool act = (c < 4) && (c <= lr);
        const float sa = act ? sAct[lrl][c] : -INFINITY;
        float M = fmaxf(m, sa);
        M = fmaxf(M, __shfl_xor(M, 1));
        M = fmaxf(M, __shfl_xor(M, 2));
        M = fmaxf(M, __shfl_xor(M, 4));
        M = fmaxf(M, __shfl_xor(M, 8));
        M = fmaxf(M, __shfl_xor(M, 16));
        const float f = __expf(m - M);
        fC[c][lrl] = f;
        const float pact = act ? __expf(sa - M) : 0.f;
        if (c < 4) pA[lrl][c] = pact;
        float l = fmaf(f, lC[c][lrl], pact);
        l += __shfl_xor(l, 1); l += __shfl_xor(l, 2);
        l += __shfl_xor(l, 4); l += __shfl_xor(l, 8); l += __shfl_xor(l, 16);
        if (c == 0) invL[lrl] = 1.f / l;
    }
    __syncthreads();

    const int d = t;                     // 0..127
    float o0 = 0.f, o1 = 0.f;
#pragma unroll 4
    for (int c = 0; c < NCH; c++) {
        const float* pa = p3 + c * 2080 + 32 + (g * 4 + lr0) * HD + d;
        o0 = fmaf(fC[c][0], pa[0],  o0);
        o1 = fmaf(fC[c][1], pa[HD], o1);
    }
#pragma unroll
    for (int k = 0; k < 4; k++) {
        const float v = vA[k][d];
        o0 = fmaf(pA[0][k], v, o0);
        o1 = fmaf(pA[1][k], v, o1);
    }
    attn[(size_t)(b * 4 + lr0) * HID + (kvh * 4 + g) * HD + d] = o0 * invL[0];
    attn[(size_t)(b * 4 + lr1) * HID + (kvh * 4 + g) * HD + d] = o1 * invL[1];
}

// ---------------------------------------------------------------------------
// K5: output projection split-K partials.  part[NKCO][16][4096]
// grid (16, 64) x 128 = 1024 blocks = 4 blocks/CU = 2 waves/SIMD.
// ---------------------------------------------------------------------------
__global__ __launch_bounds__(128)
void k_out_partial(const float* __restrict__ attn,
                   const float* __restrict__ wo,
                   float* __restrict__ part)
{
    const int t = threadIdx.x;
    const int col = blockIdx.x * 256 + t * 2;
    const int kc = blockIdx.y;
    const int k0 = kc * KCO;
    const float* wp = wo + col + (size_t)k0 * HID;

    float acc[NROWS][2];
#pragma unroll
    for (int m = 0; m < NROWS; m++) { acc[m][0] = 0.f; acc[m][1] = 0.f; }
#pragma unroll 4
    for (int kk = 0; kk < KCO; kk += 4) {
        const float2 w0 = *(const float2*)(wp + (size_t)(kk + 0) * HID);
        const float2 w1 = *(const float2*)(wp + (size_t)(kk + 1) * HID);
        const float2 w2 = *(const float2*)(wp + (size_t)(kk + 2) * HID);
        const float2 w3 = *(const float2*)(wp + (size_t)(kk + 3) * HID);
#pragma unroll
        for (int m = 0; m < NROWS; m++) {
            const float4 h4 = *(const float4*)(attn + (size_t)m * HID + k0 + kk);
            acc[m][0] = fmaf(h4.x, w0.x, fmaf(h4.y, w1.x, fmaf(h4.z, w2.x, fmaf(h4.w, w3.x, acc[m][0]))));
            acc[m][1] = fmaf(h4.x, w0.y, fmaf(h4.y, w1.y, fmaf(h4.z, w2.y, fmaf(h4.w, w3.y, acc[m][1]))));
        }
    }
    float* po = part + (size_t)kc * (NROWS * HID) + col;
#pragma unroll
    for (int m = 0; m < NROWS; m++)
        *(float2*)(po + (size_t)m * HID) = make_float2(acc[m][0], acc[m][1]);
}

// K5b: reduce out-proj partials -> d_out.  4 lanes per float4 output,
// shfl_xor(16/32) combine.  256 blocks x 256 = 1 block/CU.
__global__ __launch_bounds__(256)
void k_out_reduce(const float* __restrict__ part, float* __restrict__ out)
{
    const int tid = blockIdx.x * 256 + threadIdx.x;   // 65536
    const int w = tid >> 6, lane = tid & 63;
    const int oid = w * 16 + (lane & 15);             // float4 id, 0..16383
    const int sub = lane >> 4;
    const float* p = part + (size_t)oid * 4 + (size_t)(sub * 16) * (NROWS * HID);
    float4 s = make_float4(0.f, 0.f, 0.f, 0.f);
#pragma unroll 8
    for (int c = 0; c < 16; c++) {
        const float4 a = *(const float4*)(p + (size_t)c * (NROWS * HID));
        s.x += a.x; s.y += a.y; s.z += a.z; s.w += a.w;
    }
    s.x += __shfl_xor(s.x, 16); s.x += __shfl_xor(s.x, 32);
    s.y += __shfl_xor(s.y, 16); s.y += __shfl_xor(s.y, 32);
    s.z += __shfl_xor(s.z, 16); s.z += __shfl_xor(s.z, 32);
    s.w += __shfl_xor(s.w, 16); s.w += __shfl_xor(s.w, 32);
    if (sub == 0) *(float4*)(out + (size_t)oid * 4) = s;
}

// ---------------------------------------------------------------------------
extern "C" void kernel_launch(void* const* d_in, const int* in_sizes, int n_in,
                              void* d_out, int out_size, void* d_ws, size_t ws_size,
                              hipStream_t stream)
{
    (void)in_sizes; (void)n_in; (void)out_size; (void)ws_size;
    const float* hid = (const float*)d_in[0];
    const float* pk  = (const float*)d_in[1];
    const float* pv  = (const float*)d_in[2];
    const float* wq  = (const float*)d_in[3];
    const float* wk  = (const float*)d_in[4];
    const float* wv  = (const float*)d_in[5];
    const float* wo  = (const float*)d_in[6];
    float* out = (float*)d_out;
    float* ws  = (float*)d_ws;

    // workspace (floats); sequential lifetimes share region 0:
    //   P1 [k1->k2] 6,291,456 | P3 [k3->k4] 2,129,920 | P5 [k5->k5b] 4,194,304
    float* P1   = ws;
    float* P3   = ws;
    float* P5   = ws;
    float* qkv  = ws + 6291456;            // 98,304
    float* attn = ws + 6389760;            // 65,536   (total 25.8 MB)

    k_qkv_partial<<<dim3(24, NKCQ), 128, 0, stream>>>(hid, wq, wk, wv, P1);
    k_reduce_rope<<<896, 256, 0, stream>>>(P1, qkv);
    k_attn_prior<<<dim3(NCH, NKV, 4), 256, 0, stream>>>(qkv, pk, pv, P3);
    k_combine<<<256, 128, 0, stream>>>(qkv, P3, attn);
    k_out_partial<<<dim3(16, NKCO), 128, 0, stream>>>(attn, wo, P5);
    k_out_reduce<<<256, 256, 0, stream>>>(P5, out);
}